// Round 1
// baseline (236.698 us; speedup 1.0000x reference)
//
#include <hip/hip_runtime.h>

#define ALPHA 10.0f
#define BN_EPS 1e-5f
#define NVOX 32768   // 32*32*32
#define MDB 4096
#define CDIM 8

// ---------------- dbdb precompute ----------------
__global__ __launch_bounds__(256) void k_dbdb(const float* __restrict__ db,
                                              float* __restrict__ dbdb) {
  int j = blockIdx.x * 256 + threadIdx.x;
  const float* r = db + j * CDIM;
  float s = 0.f;
#pragma unroll
  for (int k = 0; k < CDIM; ++k) s = fmaf(r[k], r[k], s);
  dbdb[j] = s;
}

// ---------------- conv1: 2->16, k3, pad1, +BN+ReLU ----------------
__global__ __launch_bounds__(256) void k_conv1(
    const float* __restrict__ bg, const float* __restrict__ ed,
    const float* __restrict__ w1, const float* __restrict__ b1,
    const float* __restrict__ g1, const float* __restrict__ be1,
    const float* __restrict__ m1, const float* __restrict__ v1,
    float* __restrict__ A) {
  __shared__ float wT[54 * 16];  // [c*27+kk][o]
  __shared__ float sc[16], sh[16];
  int t = threadIdx.x;
  for (int i = t; i < 864; i += 256) {
    int o = i & 15, r = i >> 4;       // r = c*27+kk
    wT[i] = w1[o * 54 + r];
  }
  if (t < 16) {
    float s = g1[t] * rsqrtf(v1[t] + BN_EPS);
    sc[t] = s;
    sh[t] = (b1[t] - m1[t]) * s + be1[t];
  }
  __syncthreads();
  int v = blockIdx.x * 256 + t;
  int x = v & 31, y = (v >> 5) & 31, z = v >> 10;
  float acc[16];
#pragma unroll
  for (int o = 0; o < 16; ++o) acc[o] = 0.f;
#pragma unroll 1
  for (int k = 0; k < 27; ++k) {
    int dz = k / 9 - 1, dy = (k / 3) % 3 - 1, dx = k % 3 - 1;
    int zz = z + dz, yy = y + dy, xx = x + dx;
    bool inb = (unsigned)zz < 32u && (unsigned)yy < 32u && (unsigned)xx < 32u;
    int vv = zz * 1024 + yy * 32 + xx;
#pragma unroll
    for (int c = 0; c < 2; ++c) {
      const float* in = c ? ed : bg;
      float val = inb ? in[vv] : 0.f;
      const float4* wp = (const float4*)&wT[(c * 27 + k) * 16];
      float4 wa = wp[0], wb = wp[1], wc = wp[2], wd = wp[3];
      acc[0] = fmaf(val, wa.x, acc[0]);  acc[1] = fmaf(val, wa.y, acc[1]);
      acc[2] = fmaf(val, wa.z, acc[2]);  acc[3] = fmaf(val, wa.w, acc[3]);
      acc[4] = fmaf(val, wb.x, acc[4]);  acc[5] = fmaf(val, wb.y, acc[5]);
      acc[6] = fmaf(val, wb.z, acc[6]);  acc[7] = fmaf(val, wb.w, acc[7]);
      acc[8] = fmaf(val, wc.x, acc[8]);  acc[9] = fmaf(val, wc.y, acc[9]);
      acc[10] = fmaf(val, wc.z, acc[10]); acc[11] = fmaf(val, wc.w, acc[11]);
      acc[12] = fmaf(val, wd.x, acc[12]); acc[13] = fmaf(val, wd.y, acc[13]);
      acc[14] = fmaf(val, wd.z, acc[14]); acc[15] = fmaf(val, wd.w, acc[15]);
    }
  }
#pragma unroll
  for (int o = 0; o < 16; ++o) {
    float y2 = fmaf(acc[o], sc[o], sh[o]);
    A[o * NVOX + v] = y2 > 0.f ? y2 : 0.f;
  }
}

// ---------------- conv2: 16->32, k3, pad1, +BN+ReLU (half of out-chs per block set) ----------------
__global__ __launch_bounds__(256) void k_conv2(
    const float* __restrict__ A, const float* __restrict__ w2,
    const float* __restrict__ b2, const float* __restrict__ g2,
    const float* __restrict__ be2, const float* __restrict__ m2,
    const float* __restrict__ v2, float* __restrict__ B) {
  __shared__ float wT[432 * 16];  // [ci*27+kk][o16]
  __shared__ float sc[16], sh[16];
  int t = threadIdx.x;
  int h = blockIdx.x >> 7;   // 0/1 -> which 16 output channels
  int vb = blockIdx.x & 127;
  for (int i = t; i < 6912; i += 256) {
    int o = i & 15, r = i >> 4;  // r = ci*27+kk
    wT[i] = w2[(h * 16 + o) * 432 + r];
  }
  if (t < 16) {
    int o = h * 16 + t;
    float s = g2[o] * rsqrtf(v2[o] + BN_EPS);
    sc[t] = s;
    sh[t] = (b2[o] - m2[o]) * s + be2[o];
  }
  __syncthreads();
  int v = vb * 256 + t;
  int x = v & 31, y = (v >> 5) & 31, z = v >> 10;
  float acc[16];
#pragma unroll
  for (int o = 0; o < 16; ++o) acc[o] = 0.f;
#pragma unroll 1
  for (int k = 0; k < 27; ++k) {
    int dz = k / 9 - 1, dy = (k / 3) % 3 - 1, dx = k % 3 - 1;
    int zz = z + dz, yy = y + dy, xx = x + dx;
    bool inb = (unsigned)zz < 32u && (unsigned)yy < 32u && (unsigned)xx < 32u;
    int vv = zz * 1024 + yy * 32 + xx;
#pragma unroll
    for (int ci = 0; ci < 16; ++ci) {
      float val = inb ? A[ci * NVOX + vv] : 0.f;
      const float4* wp = (const float4*)&wT[(ci * 27 + k) * 16];
      float4 wa = wp[0], wb = wp[1], wc = wp[2], wd = wp[3];
      acc[0] = fmaf(val, wa.x, acc[0]);  acc[1] = fmaf(val, wa.y, acc[1]);
      acc[2] = fmaf(val, wa.z, acc[2]);  acc[3] = fmaf(val, wa.w, acc[3]);
      acc[4] = fmaf(val, wb.x, acc[4]);  acc[5] = fmaf(val, wb.y, acc[5]);
      acc[6] = fmaf(val, wb.z, acc[6]);  acc[7] = fmaf(val, wb.w, acc[7]);
      acc[8] = fmaf(val, wc.x, acc[8]);  acc[9] = fmaf(val, wc.y, acc[9]);
      acc[10] = fmaf(val, wc.z, acc[10]); acc[11] = fmaf(val, wc.w, acc[11]);
      acc[12] = fmaf(val, wd.x, acc[12]); acc[13] = fmaf(val, wd.y, acc[13]);
      acc[14] = fmaf(val, wd.z, acc[14]); acc[15] = fmaf(val, wd.w, acc[15]);
    }
  }
#pragma unroll
  for (int o = 0; o < 16; ++o) {
    float y2 = fmaf(acc[o], sc[o], sh[o]);
    B[(h * 16 + o) * NVOX + v] = y2 > 0.f ? y2 : 0.f;
  }
}

// ---------------- conv3 (1x1x1) 32->8 + L2 normalize ----------------
__global__ __launch_bounds__(256) void k_conv3(
    const float* __restrict__ B, const float* __restrict__ w3,
    const float* __restrict__ b3, float* __restrict__ Q) {
  __shared__ float wT[32 * 8];  // [ci][o]
  __shared__ float bL[8];
  int t = threadIdx.x;
  if (t < 256) {
    int o = t & 7, ci = t >> 3;
    wT[t] = w3[o * 32 + ci];
  }
  if (t < 8) bL[t] = b3[t];
  __syncthreads();
  int v = blockIdx.x * 256 + t;
  float lat[8];
#pragma unroll
  for (int o = 0; o < 8; ++o) lat[o] = bL[o];
#pragma unroll 4
  for (int ci = 0; ci < 32; ++ci) {
    float val = B[ci * NVOX + v];
    const float4* wp = (const float4*)&wT[ci * 8];
    float4 wa = wp[0], wb = wp[1];
    lat[0] = fmaf(val, wa.x, lat[0]); lat[1] = fmaf(val, wa.y, lat[1]);
    lat[2] = fmaf(val, wa.z, lat[2]); lat[3] = fmaf(val, wa.w, lat[3]);
    lat[4] = fmaf(val, wb.x, lat[4]); lat[5] = fmaf(val, wb.y, lat[5]);
    lat[6] = fmaf(val, wb.z, lat[6]); lat[7] = fmaf(val, wb.w, lat[7]);
  }
  float n2 = 0.f;
#pragma unroll
  for (int o = 0; o < 8; ++o) n2 = fmaf(lat[o], lat[o], n2);
  float inv = 1.f / fmaxf(sqrtf(n2), 1e-12f);
  float4 qa, qb;
  qa.x = lat[0] * inv; qa.y = lat[1] * inv; qa.z = lat[2] * inv; qa.w = lat[3] * inv;
  qb.x = lat[4] * inv; qb.y = lat[5] * inv; qb.z = lat[6] * inv; qb.w = lat[7] * inv;
  ((float4*)(Q + (size_t)v * 8))[0] = qa;
  ((float4*)(Q + (size_t)v * 8))[1] = qb;
}

// ---------------- kNN partial: thread per (query, chunk), sorted top-10 ----------------
__global__ __launch_bounds__(256) void k_knn(
    const float* __restrict__ Q, const float* __restrict__ db,
    const float* __restrict__ dbdb, float* __restrict__ pd,
    int* __restrict__ pi, int nchunk) {
  int t = threadIdx.x;
  int c = blockIdx.x >> 7;            // chunk id
  int v = (blockIdx.x & 127) * 256 + t;
  int L = MDB / nchunk;
  int j0 = c * L, j1 = j0 + L;
  float4 qa = ((const float4*)(Q + (size_t)v * 8))[0];
  float4 qb = ((const float4*)(Q + (size_t)v * 8))[1];
  float qq = qa.x * qa.x;
  qq = fmaf(qa.y, qa.y, qq); qq = fmaf(qa.z, qa.z, qq); qq = fmaf(qa.w, qa.w, qq);
  qq = fmaf(qb.x, qb.x, qq); qq = fmaf(qb.y, qb.y, qq);
  qq = fmaf(qb.z, qb.z, qq); qq = fmaf(qb.w, qb.w, qq);

  float d[10];
  int ix[10];
#pragma unroll
  for (int k = 0; k < 10; ++k) { d[k] = 3.4e38f; ix[k] = 0; }

#pragma unroll 2
  for (int j = j0; j < j1; ++j) {
    const float4* rp = (const float4*)(db + (size_t)j * 8);
    float4 r0 = rp[0], r1 = rp[1];
    float dot = qa.x * r0.x;
    dot = fmaf(qa.y, r0.y, dot); dot = fmaf(qa.z, r0.z, dot);
    dot = fmaf(qa.w, r0.w, dot); dot = fmaf(qb.x, r1.x, dot);
    dot = fmaf(qb.y, r1.y, dot); dot = fmaf(qb.z, r1.z, dot);
    dot = fmaf(qb.w, r1.w, dot);
    float d2 = fmaf(-2.f, dot, qq + dbdb[j]);
    if (d2 < d[9]) {
      float nd = d2; int ni = j;
      bool cn = true;  // nd < old d[k] of the step above (starts: guard)
#pragma unroll
      for (int k = 9; k >= 1; --k) {
        bool c1 = nd < d[k - 1];
        float dn = c1 ? d[k - 1] : (cn ? nd : d[k]);
        int in_ = c1 ? ix[k - 1] : (cn ? ni : ix[k]);
        d[k] = dn; ix[k] = in_;
        cn = c1;
      }
      if (cn) { d[0] = nd; ix[0] = ni; }
    }
  }
  size_t base = ((size_t)c * NVOX + v) * 10;
#pragma unroll
  for (int k = 0; k < 10; ++k) { pd[base + k] = d[k]; pi[base + k] = ix[k]; }
}

// ---------------- merge partials + weighted label average ----------------
__global__ __launch_bounds__(256) void k_merge(
    const float* __restrict__ pd, const int* __restrict__ pi,
    const float* __restrict__ labels, float* __restrict__ out, int nchunk) {
  int v = blockIdx.x * 256 + threadIdx.x;
  float d[10];
  int ix[10];
#pragma unroll
  for (int k = 0; k < 10; ++k) { d[k] = 3.4e38f; ix[k] = 0; }
#pragma unroll 1
  for (int c = 0; c < nchunk; ++c) {
    size_t base = ((size_t)c * NVOX + v) * 10;
#pragma unroll 1
    for (int k2 = 0; k2 < 10; ++k2) {
      float nd = pd[base + k2];
      int ni = pi[base + k2];
      if (nd < d[9]) {
        bool cn = true;
#pragma unroll
        for (int k = 9; k >= 1; --k) {
          bool c1 = nd < d[k - 1];
          float dn = c1 ? d[k - 1] : (cn ? nd : d[k]);
          int in_ = c1 ? ix[k - 1] : (cn ? ni : ix[k]);
          d[k] = dn; ix[k] = in_;
          cn = c1;
        }
        if (cn) { d[0] = nd; ix[0] = ni; }
      }
    }
  }
  float num = 0.f, den = 0.f;
#pragma unroll
  for (int k = 0; k < 10; ++k) {
    float w = expf(-ALPHA * d[k]);
    num = fmaf(w, labels[ix[k]], num);
    den += w;
  }
  out[v] = num / (den + 1e-8f);
}

extern "C" void kernel_launch(void* const* d_in, const int* in_sizes, int n_in,
                              void* d_out, int out_size, void* d_ws, size_t ws_size,
                              hipStream_t stream) {
  const float* bg = (const float*)d_in[0];
  const float* ed = (const float*)d_in[1];
  // d_in[2] context_mask: unused by reference
  const float* w1 = (const float*)d_in[3];
  const float* b1 = (const float*)d_in[4];
  const float* g1 = (const float*)d_in[5];
  const float* be1 = (const float*)d_in[6];
  const float* m1 = (const float*)d_in[7];
  const float* v1 = (const float*)d_in[8];
  const float* w2 = (const float*)d_in[9];
  const float* b2 = (const float*)d_in[10];
  const float* g2 = (const float*)d_in[11];
  const float* be2 = (const float*)d_in[12];
  const float* m2 = (const float*)d_in[13];
  const float* v2 = (const float*)d_in[14];
  const float* w3 = (const float*)d_in[15];
  const float* b3 = (const float*)d_in[16];
  const float* db = (const float*)d_in[17];
  const float* labels = (const float*)d_in[18];
  float* out = (float*)d_out;

  char* ws = (char*)d_ws;
  // layout (with reuse):
  //   [0, 16K)          dbdb
  //   [16K, 16K+2M)     A (conv1 out); later reused: Q at 16K (1MB)
  //   [16K+2M, 16K+6M)  B (conv2 out)
  //   [16K+1M, ...)     partials pd/pi (A tail + B are dead by then)
  const size_t off_dbdb = 0;
  const size_t off_A = 16384;
  const size_t off_B = off_A + (size_t)16 * NVOX * 4;      // 16K + 2M
  const size_t off_Q = off_A;                               // reuse A
  const size_t off_part = off_A + (size_t)NVOX * 8 * 4;     // 16K + 1M

  // pick number of db chunks by available scratch
  size_t need4 = off_part + (size_t)4 * NVOX * 10 * 8;
  int NC = (ws_size >= need4) ? 4 : 2;

  float* dbdb = (float*)(ws + off_dbdb);
  float* A = (float*)(ws + off_A);
  float* B = (float*)(ws + off_B);
  float* Q = (float*)(ws + off_Q);
  float* pd = (float*)(ws + off_part);
  int* pi = (int*)(ws + off_part + (size_t)NC * NVOX * 10 * 4);

  k_dbdb<<<MDB / 256, 256, 0, stream>>>(db, dbdb);
  k_conv1<<<NVOX / 256, 256, 0, stream>>>(bg, ed, w1, b1, g1, be1, m1, v1, A);
  k_conv2<<<2 * (NVOX / 256), 256, 0, stream>>>(A, w2, b2, g2, be2, m2, v2, B);
  k_conv3<<<NVOX / 256, 256, 0, stream>>>(B, w3, b3, Q);
  k_knn<<<NC * (NVOX / 256), 256, 0, stream>>>(Q, db, dbdb, pd, pi, NC);
  k_merge<<<NVOX / 256, 256, 0, stream>>>(pd, pi, labels, out, NC);
}